// Round 16
// baseline (405.031 us; speedup 1.0000x reference)
//
#include <hip/hip_runtime.h>
#include <hip/hip_bf16.h>

typedef __attribute__((ext_vector_type(8))) short bf16x8;
typedef __attribute__((ext_vector_type(4))) float f32x4;
typedef __attribute__((ext_vector_type(4))) unsigned u32x4;

#define CDIM 1024
#define DDIM 1024
#define TDIM 1024
#define BK 32

__device__ __forceinline__ unsigned cvt_pk_bf16(float a, float b) {
    unsigned r;
    asm("v_cvt_pk_bf16_f32 %0, %1, %2" : "=v"(r) : "v"(a), "v"(b));
    return r;
}
__device__ __forceinline__ int swz8(int r) { return (r ^ (r >> 3)) & 7; }
__device__ __forceinline__ int swz4(int r) { return (r ^ (r >> 3)) & 3; }

// ============ prepass 1: W fp32 -> baked LDS-image chunks (hi+lo) =========
// Chunk (s*4+dt)*32+kt, 32 KB: row r (d-256dt) x 8 slots x 8 shorts;
// slot sl holds granule g = sl ^ swz8(r); g<4: hi bf16 of W[s][32kt+8g+e][.];
// g>=4: lo residual.
__global__ __launch_bounds__(512, 1)
void prep_w(const float* __restrict__ w, short* __restrict__ wopt)
{
    __shared__ float T[32 * 260];
    const int blk = blockIdx.x;     // 0..4095
    const int kt = blk & 31;
    const int dt = (blk >> 5) & 3;
    const int s  = blk >> 7;
    const float* wb = w + (size_t)s * (CDIM * DDIM)
                        + (size_t)(kt * 32) * DDIM + dt * 256;
    const int tid = threadIdx.x;
    {
        const int row = tid >> 4;
        const int seg = tid & 15;
        const float* src = wb + (size_t)row * DDIM + seg * 16;
        float4 a0 = *(const float4*)(src);
        float4 a1 = *(const float4*)(src + 4);
        float4 a2 = *(const float4*)(src + 8);
        float4 a3 = *(const float4*)(src + 12);
        float* dst = T + row * 260 + seg * 16;
        *(float4*)(dst) = a0;      *(float4*)(dst + 4) = a1;
        *(float4*)(dst + 8) = a2;  *(float4*)(dst + 12) = a3;
    }
    __syncthreads();
    short* outc = wopt + (size_t)blk * 16384;
    #pragma unroll
    for (int j = 0; j < 4; ++j) {
        const int u = tid + 512 * j;
        const int r = u >> 3;
        const int sl = u & 7;
        const int g = sl ^ swz8(r);
        const int kk = (g & 3) * 8;
        const bool hi = (g < 4);
        unsigned o[4];
        #pragma unroll
        for (int p = 0; p < 4; ++p) {
            const float f0 = T[(kk + 2 * p    ) * 260 + r];
            const float f1 = T[(kk + 2 * p + 1) * 260 + r];
            const unsigned h = cvt_pk_bf16(f0, f1);
            const float l0 = f0 - __uint_as_float(h << 16);
            const float l1 = f1 - __uint_as_float(h & 0xFFFF0000u);
            const unsigned lo = cvt_pk_bf16(l0, l1);
            o[p] = hi ? h : lo;
        }
        *(u32x4*)(outc + (size_t)u * 8) = *(u32x4*)o;
    }
}

// ============ prepass 2: X fp32 -> baked LDS-image chunks (hi only) =======
// Chunk (b*4+tt)*32+kt, 16 KB: row r (t-256tt) x 4 slots x 8 shorts;
// slot sl holds granule g = sl ^ swz4(r) = hi bf16 of X[b][32kt+8g+e][.].
__global__ __launch_bounds__(256, 2)
void prep_x(const float* __restrict__ x, short* __restrict__ xopt)
{
    __shared__ float T[32 * 260];
    const int blk = blockIdx.x;     // 0..8191
    const int kt = blk & 31;
    const int tt = (blk >> 5) & 3;
    const int b  = blk >> 7;
    const float* xb = x + (size_t)b * (CDIM * TDIM)
                        + (size_t)(kt * 32) * TDIM + tt * 256;
    const int tid = threadIdx.x;
    {
        const int row = tid >> 3;       // 0..31
        const int seg = tid & 7;        // 32 f32 each
        const float* src = xb + (size_t)row * TDIM + seg * 32;
        float* dst = T + row * 260 + seg * 32;
        #pragma unroll
        for (int i = 0; i < 8; ++i)
            *(float4*)(dst + i * 4) = *(const float4*)(src + i * 4);
    }
    __syncthreads();
    short* outc = xopt + (size_t)blk * 8192;
    #pragma unroll
    for (int j = 0; j < 4; ++j) {
        const int u = tid + 256 * j;    // 0..1023
        const int r = u >> 2;
        const int sl = u & 3;
        const int g = sl ^ swz4(r);
        const int kk = g * 8;
        unsigned o[4];
        #pragma unroll
        for (int p = 0; p < 4; ++p)
            o[p] = cvt_pk_bf16(T[(kk + 2 * p) * 260 + r],
                               T[(kk + 2 * p + 1) * 260 + r]);
        *(u32x4*)(outc + (size_t)u * 8) = *(u32x4*)o;
    }
}

// ============ main: both operands via global_load_lds, counted vmcnt ======
// out[b,d,t] ~= sum_c (Wh+Wl)[c,d]*Xh[c,t]  (2-term, r14/r15: absmax 0.03125)
// 256x256 tile, 8 waves. Per step: {issue 4 W + 2 X gload_lds -> buf Q |
// vmcnt(6) = drain LAST step's 6 into P | barrier | 16 b128 frag reads P |
// lgkmcnt(0) | barrier | 64 reg-only MFMA}. No cvt, no reg staging, no
// vmcnt(0) in loop (T3/T4). r15 lesson: reg-staged X (cvt chain + 8-way
// conflicted uint2 writes) was the exposed tax; now DMA'd like W.
#define KSTEP(P, Q, KNEXT)                                                      \
  {                                                                             \
    const int kn = (KNEXT) & (CDIM - 1);                                        \
    {                                                                           \
      const short* gw = wchunk + (size_t)(kn >> 5) * 16384 + wave * 2048 + lane * 8; \
      short* lw = &Wt[Q][wave * 2048];                                          \
      _Pragma("unroll")                                                         \
      for (int q = 0; q < 4; ++q)                                               \
        __builtin_amdgcn_global_load_lds(                                       \
            (const __attribute__((address_space(1))) void*)(gw + q * 512),      \
            (__attribute__((address_space(3))) void*)(lw + q * 512), 16, 0, 0); \
      const short* gx = xchunk + (size_t)(kn >> 5) * 8192 + wave * 1024 + lane * 8; \
      short* lx = &Xt[Q][wave * 1024];                                          \
      _Pragma("unroll")                                                         \
      for (int q = 0; q < 2; ++q)                                               \
        __builtin_amdgcn_global_load_lds(                                       \
            (const __attribute__((address_space(1))) void*)(gx + q * 512),      \
            (__attribute__((address_space(3))) void*)(lx + q * 512), 16, 0, 0); \
    }                                                                           \
    asm volatile("s_waitcnt vmcnt(6)" ::: "memory");                            \
    __builtin_amdgcn_sched_barrier(0);                                          \
    __builtin_amdgcn_s_barrier();                                               \
    __builtin_amdgcn_sched_barrier(0);                                          \
    bf16x8 ah[4], al[4], bh[8];                                                 \
    _Pragma("unroll")                                                           \
    for (int m = 0; m < 4; ++m) {                                               \
      const short* wrow = &Wt[P][(wdOff + m * 16 + fr) * 64];                   \
      ah[m] = *(const bf16x8*)(wrow + offHW[m]);                                \
      al[m] = *(const bf16x8*)(wrow + (offHW[m] ^ 32));                         \
    }                                                                           \
    _Pragma("unroll")                                                           \
    for (int n = 0; n < 8; ++n)                                                 \
      bh[n] = *(const bf16x8*)(&Xt[P][(wtOff + n * 16 + fr) * 32] + offHX[n]);  \
    asm volatile("s_waitcnt lgkmcnt(0)" ::: "memory");                          \
    __builtin_amdgcn_sched_barrier(0);                                          \
    __builtin_amdgcn_s_barrier();                                               \
    __builtin_amdgcn_sched_barrier(0);                                          \
    _Pragma("unroll")                                                           \
    for (int np = 0; np < 4; ++np) {                                            \
      const int n0 = 2 * np, n1 = 2 * np + 1;                                   \
      _Pragma("unroll")                                                         \
      for (int m = 0; m < 4; ++m)                                               \
        acc[m][n0] = __builtin_amdgcn_mfma_f32_16x16x32_bf16(ah[m], bh[n0], acc[m][n0], 0, 0, 0); \
      _Pragma("unroll")                                                         \
      for (int m = 0; m < 4; ++m)                                               \
        acc[m][n1] = __builtin_amdgcn_mfma_f32_16x16x32_bf16(ah[m], bh[n1], acc[m][n1], 0, 0, 0); \
      _Pragma("unroll")                                                         \
      for (int m = 0; m < 4; ++m)                                               \
        acc[m][n0] = __builtin_amdgcn_mfma_f32_16x16x32_bf16(al[m], bh[n0], acc[m][n0], 0, 0, 0); \
      _Pragma("unroll")                                                         \
      for (int m = 0; m < 4; ++m)                                               \
        acc[m][n1] = __builtin_amdgcn_mfma_f32_16x16x32_bf16(al[m], bh[n1], acc[m][n1], 0, 0, 0); \
    }                                                                           \
  }

__global__ __launch_bounds__(512, 1)
void subject_gemm3(const int* __restrict__ subj, const short* __restrict__ wopt,
                   const short* __restrict__ xopt, float* __restrict__ out)
{
    __shared__ short Wt[2][256 * 64];   // 2 x 32 KB
    __shared__ short Xt[2][256 * 32];   // 2 x 16 KB

    const int bid = blockIdx.x;
    const int xcd = bid & 7;
    const int slot = bid >> 3;
    const int b = (xcd << 3) | (slot >> 4);
    const int r = slot & 15;
    const int dtIdx = r >> 2;
    const int ttIdx = r & 3;
    const int dtile = dtIdx << 8;
    const int ttile = ttIdx << 8;

    const int s = subj[b];
    const short* __restrict__ wchunk = wopt + (size_t)((s * 4 + dtIdx) * 32) * 16384;
    const short* __restrict__ xchunk = xopt + (size_t)((b * 4 + ttIdx) * 32) * 8192;

    const int tid = threadIdx.x;
    const int lane = tid & 63;
    const int wave = tid >> 6;

    const int wdOff = (wave >> 1) << 6;
    const int wtOff = (wave & 1) << 7;
    const int fr = lane & 15;
    const int fg = lane >> 4;

    int offHW[4], offHX[8];
    #pragma unroll
    for (int m = 0; m < 4; ++m) {
        const int rowW = wdOff + m * 16 + fr;
        offHW[m] = ((fg ^ swz8(rowW)) << 3);
    }
    #pragma unroll
    for (int n = 0; n < 8; ++n) {
        const int rowX = wtOff + n * 16 + fr;
        offHX[n] = ((fg ^ swz4(rowX)) << 3);
    }

    f32x4 acc[4][8] = {};

    // prologue: DMA step 0 into buf 0
    {
        const short* gw = wchunk + wave * 2048 + lane * 8;
        short* lw = &Wt[0][wave * 2048];
        #pragma unroll
        for (int q = 0; q < 4; ++q)
            __builtin_amdgcn_global_load_lds(
                (const __attribute__((address_space(1))) void*)(gw + q * 512),
                (__attribute__((address_space(3))) void*)(lw + q * 512), 16, 0, 0);
        const short* gx = xchunk + wave * 1024 + lane * 8;
        short* lx = &Xt[0][wave * 1024];
        #pragma unroll
        for (int q = 0; q < 2; ++q)
            __builtin_amdgcn_global_load_lds(
                (const __attribute__((address_space(1))) void*)(gx + q * 512),
                (__attribute__((address_space(3))) void*)(lx + q * 512), 16, 0, 0);
    }
    asm volatile("s_waitcnt vmcnt(0)" ::: "memory");
    __builtin_amdgcn_sched_barrier(0);
    __builtin_amdgcn_s_barrier();
    __builtin_amdgcn_sched_barrier(0);

    for (int k0 = 0; k0 < CDIM; k0 += 2 * BK) {
        KSTEP(0, 1, k0 + BK);
        KSTEP(1, 0, k0 + 2 * BK);
    }

    float* __restrict__ oB = out + (size_t)b * (DDIM * TDIM)
                           + (size_t)(dtile + wdOff) * TDIM + (ttile + wtOff);
    #pragma unroll
    for (int m = 0; m < 4; ++m) {
        #pragma unroll
        for (int q = 0; q < 4; ++q) {
            const int d = m * 16 + (fg << 2) + q;
            float* orow = oB + (size_t)d * TDIM;
            #pragma unroll
            for (int n = 0; n < 8; ++n) {
                orow[n * 16 + fr] = acc[m][n][q];
            }
        }
    }
}

// ============ fallback: round-9 proven chassis (377 us) ====================
#define FKSTEP(VCUR, VNXT, K0)                                                  \
  {                                                                             \
    const int ksafe = ((K0) + BK) & (CDIM - 1);                                 \
    _Pragma("unroll")                                                           \
    for (int j = 0; j < 8; ++j)                                                 \
        VNXT[j] = *(const float4*)(sp + ((size_t)(ksafe + (cg << 3) + j) << 10)); \
    u32x4 hg[4], lg[4];                                                         \
    _Pragma("unroll")                                                           \
    for (int rr = 0; rr < 4; ++rr) {                                            \
      _Pragma("unroll")                                                         \
      for (int p = 0; p < 4; ++p) {                                             \
        const float f0 = VCUR[2 * p][rr];                                       \
        const float f1 = VCUR[2 * p + 1][rr];                                   \
        const unsigned h = cvt_pk_bf16(f0, f1);                                 \
        const float l0 = f0 - __uint_as_float(h << 16);                         \
        const float l1 = f1 - __uint_as_float(h & 0xFFFF0000u);                 \
        hg[rr][p] = h;                                                          \
        lg[rr][p] = cvt_pk_bf16(l0, l1);                                        \
      }                                                                         \
    }                                                                           \
    __syncthreads();                                                            \
    _Pragma("unroll")                                                           \
    for (int rr = 0; rr < 4; ++rr) {                                            \
      const int row = col0 + rr;                                                \
      short* sl = slds + row * 64;                                              \
      const int so = ((cg ^ swz8(row)) << 3);                                   \
      *(u32x4*)(sl + so) = hg[rr];                                              \
      *(u32x4*)(sl + (so ^ 32)) = lg[rr];                                       \
    }                                                                           \
    __syncthreads();                                                            \
    bf16x8 ah[4], al[4];                                                        \
    _Pragma("unroll")                                                           \
    for (int m = 0; m < 4; ++m) {                                               \
      const short* wrow = Wt + (wdOff + m * 16 + fr) * 64;                      \
      ah[m] = *(const bf16x8*)(wrow + offHW[m]);                                \
      al[m] = *(const bf16x8*)(wrow + (offHW[m] ^ 32));                         \
    }                                                                           \
    _Pragma("unroll")                                                           \
    for (int np = 0; np < 4; ++np) {                                            \
      const int n0 = 2 * np, n1 = 2 * np + 1;                                   \
      const short* xr0 = Xt + (wtOff + n0 * 16 + fr) * 64;                      \
      const short* xr1 = Xt + (wtOff + n1 * 16 + fr) * 64;                      \
      const bf16x8 bh0 = *(const bf16x8*)(xr0 + offHX[n0]);                     \
      const bf16x8 bl0 = *(const bf16x8*)(xr0 + (offHX[n0] ^ 32));              \
      const bf16x8 bh1 = *(const bf16x8*)(xr1 + offHX[n1]);                     \
      const bf16x8 bl1 = *(const bf16x8*)(xr1 + (offHX[n1] ^ 32));              \
      _Pragma("unroll")                                                         \
      for (int m = 0; m < 4; ++m)                                               \
        acc[m][n0] = __builtin_amdgcn_mfma_f32_16x16x32_bf16(ah[m], bh0, acc[m][n0], 0, 0, 0); \
      _Pragma("unroll")                                                         \
      for (int m = 0; m < 4; ++m)                                               \
        acc[m][n1] = __builtin_amdgcn_mfma_f32_16x16x32_bf16(ah[m], bh1, acc[m][n1], 0, 0, 0); \
      _Pragma("unroll")                                                         \
      for (int m = 0; m < 4; ++m)                                               \
        acc[m][n0] = __builtin_amdgcn_mfma_f32_16x16x32_bf16(ah[m], bl0, acc[m][n0], 0, 0, 0); \
      _Pragma("unroll")                                                         \
      for (int m = 0; m < 4; ++m)                                               \
        acc[m][n1] = __builtin_amdgcn_mfma_f32_16x16x32_bf16(ah[m], bl1, acc[m][n1], 0, 0, 0); \
      _Pragma("unroll")                                                         \
      for (int m = 0; m < 4; ++m)                                               \
        acc[m][n0] = __builtin_amdgcn_mfma_f32_16x16x32_bf16(al[m], bh0, acc[m][n0], 0, 0, 0); \
      _Pragma("unroll")                                                         \
      for (int m = 0; m < 4; ++m)                                               \
        acc[m][n1] = __builtin_amdgcn_mfma_f32_16x16x32_bf16(al[m], bh1, acc[m][n1], 0, 0, 0); \
    }                                                                           \
  }

__global__ __launch_bounds__(512, 1)
void subject_gemm_fb(const float* __restrict__ x, const int* __restrict__ subj,
                     const float* __restrict__ w, float* __restrict__ out)
{
    __shared__ short Wt[256 * 64];
    __shared__ short Xt[256 * 64];

    const int bid = blockIdx.x;
    const int xcd = bid & 7;
    const int slot = bid >> 3;
    const int b = (xcd << 3) | (slot >> 4);
    const int r = slot & 15;
    const int dtile = (r >> 2) << 8;
    const int ttile = (r & 3) << 8;

    const int s = subj[b];
    const float* __restrict__ wB = w + (size_t)s * (CDIM * DDIM);
    const float* __restrict__ xB = x + (size_t)b * (CDIM * TDIM);

    const int tid = threadIdx.x;
    const int lane = tid & 63;
    const int wave = tid >> 6;

    const int ht = tid & 255;
    const int tq = ht & 63;
    const int cg = ht >> 6;
    const int col0 = tq << 2;
    const bool isW = (tid < 256);
    const float* sp = (isW ? wB + dtile : xB + ttile) + col0;
    short* slds = (isW ? Wt : Xt);

    const int wdOff = (wave >> 1) << 6;
    const int wtOff = (wave & 1) << 7;
    const int fr = lane & 15;
    const int fg = lane >> 4;

    int offHW[4], offHX[8];
    #pragma unroll
    for (int m = 0; m < 4; ++m) {
        const int rowW = wdOff + m * 16 + fr;
        offHW[m] = ((fg ^ swz8(rowW)) << 3);
    }
    #pragma unroll
    for (int n = 0; n < 8; ++n) {
        const int rowX = wtOff + n * 16 + fr;
        offHX[n] = ((fg ^ swz8(rowX)) << 3);
    }

    f32x4 acc[4][8] = {};

    float4 va[8], vb[8];
    #pragma unroll
    for (int j = 0; j < 8; ++j)
        va[j] = *(const float4*)(sp + ((size_t)((cg << 3) + j) << 10));

    for (int k0 = 0; k0 < CDIM; k0 += 2 * BK) {
        FKSTEP(va, vb, k0);
        FKSTEP(vb, va, k0 + BK);
    }

    float* __restrict__ oB = out + (size_t)b * (DDIM * TDIM)
                           + (size_t)(dtile + wdOff) * TDIM + (ttile + wtOff);
    #pragma unroll
    for (int m = 0; m < 4; ++m) {
        #pragma unroll
        for (int q = 0; q < 4; ++q) {
            const int d = m * 16 + (fg << 2) + q;
            float* orow = oB + (size_t)d * TDIM;
            #pragma unroll
            for (int n = 0; n < 8; ++n) {
                orow[n * 16 + fr] = acc[m][n][q];
            }
        }
    }
}

extern "C" void kernel_launch(void* const* d_in, const int* in_sizes, int n_in,
                              void* d_out, int out_size, void* d_ws, size_t ws_size,
                              hipStream_t stream) {
    const float* x = (const float*)d_in[0];
    const int* subjects = (const int*)d_in[1];
    const float* w = (const float*)d_in[2];
    float* out = (float*)d_out;
    const size_t NEED_W = (size_t)4096 * 32768;            // 128 MiB
    const size_t NEED_FULL = NEED_W + (size_t)8192 * 16384; // 256 MiB
    short* wopt = (short*)d_ws;
    short* xopt = (short*)d_ws + (size_t)4096 * 16384;     // after W images
    if (ws_size >= NEED_FULL) {
        prep_w<<<dim3(4096), dim3(512), 0, stream>>>(w, wopt);
        prep_x<<<dim3(8192), dim3(256), 0, stream>>>(x, xopt);
        subject_gemm3<<<dim3(1024), dim3(512), 0, stream>>>(subjects, wopt, xopt, out);
    } else {
        subject_gemm_fb<<<dim3(1024), dim3(512), 0, stream>>>(x, subjects, w, out);
    }
}